// Round 1
// baseline (537.927 us; speedup 1.0000x reference)
//
#include <hip/hip_runtime.h>
#include <math.h>

#define B_    128
#define N_    1369
#define DINO_ 384
#define CLIP_ 512
#define H_    8
#define CHUNKS 6
#define CH     229   // ceil(1369/6); last chunk = 224
#define SMP    52    // padded per-lane float stride in merge LDS (16B aligned, conflict-free)

// ---------------------------------------------------------------------------
// helpers
// ---------------------------------------------------------------------------
__device__ __forceinline__ float wave_sum(float v) {
  v += __shfl_xor(v, 1);  v += __shfl_xor(v, 2);  v += __shfl_xor(v, 4);
  v += __shfl_xor(v, 8);  v += __shfl_xor(v, 16); v += __shfl_xor(v, 32);
  return v;
}

// ---------------------------------------------------------------------------
// kq: Q[b,c] = bq[c] + clip[b,:]·Wq[:,c].  grid (128,2) x 256.
// ---------------------------------------------------------------------------
__global__ __launch_bounds__(256) void kq(const float* __restrict__ clip,
                                          const float* __restrict__ Wq,
                                          const float* __restrict__ bq,
                                          float* __restrict__ Q) {
  const int b = blockIdx.x;
  const int c = blockIdx.y * 256 + threadIdx.x;
  __shared__ float cl[CLIP_];
  cl[threadIdx.x] = clip[b * CLIP_ + threadIdx.x];
  cl[threadIdx.x + 256] = clip[b * CLIP_ + threadIdx.x + 256];
  __syncthreads();
  float acc = bq[c];
  #pragma unroll 8
  for (int j = 0; j < CLIP_; ++j) acc += cl[j] * Wq[j * CLIP_ + c];
  Q[b * CLIP_ + c] = acc;
}

// ---------------------------------------------------------------------------
// kqk: qk[b, h*384+j] = rs * sum_d Wk[j][h*64+d] * Q[b, h*64+d].
// Reads Wk directly (row slice of 64 consecutive floats, L2-resident) —
// the separate transpose kernel is gone.  grid (128,12) x 256.
// ---------------------------------------------------------------------------
__global__ __launch_bounds__(256) void kqk(const float* __restrict__ Wk,
                                           const float* __restrict__ Q,
                                           const float* __restrict__ temp,
                                           float* __restrict__ qkout) {
  const int b = blockIdx.x;
  const int e = blockIdx.y * 256 + threadIdx.x;   // 0..3071
  __shared__ float qs[CLIP_];
  qs[threadIdx.x] = Q[b * CLIP_ + threadIdx.x];
  qs[threadIdx.x + 256] = Q[b * CLIP_ + threadIdx.x + 256];
  __syncthreads();
  const int h = e / DINO_;
  const int j = e - h * DINO_;
  const float rs = 1.0f / (8.0f * temp[0]);       // scale = sqrt(64)*temperature
  const float* wrow = Wk + (size_t)j * CLIP_ + h * 64;
  const float* qrow = qs + h * 64;
  float a0 = 0.f, a1 = 0.f, a2 = 0.f, a3 = 0.f;
  #pragma unroll
  for (int d = 0; d < 64; d += 4) {
    const float4 wv = *(const float4*)(wrow + d);
    const float4 qv = *(const float4*)(qrow + d);
    a0 += wv.x * qv.x;  a1 += wv.y * qv.y;
    a2 += wv.z * qv.z;  a3 += wv.w * qv.w;
  }
  qkout[(size_t)b * 3072 + e] = ((a0 + a1) + (a2 + a3)) * rs;
}

// ---------------------------------------------------------------------------
// kmain: fused logits + (no-max) softmax numerator + attn-weighted dino sum.
// grid 768 x 256 (3 blocks/CU, 12 waves/CU at launch_bounds(256,3)).
//
// Lane layout: h = lane>>3 (head), sl = lane&7.  Each 8-lane head-group
// covers the 384-dim row with interleaved float4 slices:
//   dim(t,z) = 4*(sl + 8*t) + z,  t=0..11, z=0..3.
// Per load instruction the 8 sl-values form one contiguous 128B run; the 8
// head-groups read identical addresses (cache-line broadcast, no extra HBM).
// Head logit reduction = 3 xor-shuffles over the 8-lane group (vs 24 before).
// ---------------------------------------------------------------------------
__global__ __launch_bounds__(256, 3) void kmain(const float* __restrict__ dino,
                                                const float* __restrict__ qk,
                                                float* __restrict__ ps,
                                                float* __restrict__ pl) {
  const int blk = blockIdx.x;
  const int b = blk / CHUNKS;
  const int c = blk - b * CHUNKS;
  const int n0 = c * CH;
  const int n1 = min(N_, n0 + CH);
  const int tid = threadIdx.x, w = tid >> 6, lane = tid & 63;
  const int h = lane >> 3, sl = lane & 7;
  const int off = 4 * sl;   // float offset of this lane's float4 within each 32-float strip

  // qk fragment: qr[4t+z] = qk[b][h*384 + 32t + 4sl + z]
  float qr[48];
  {
    const float* qb = qk + (size_t)b * 3072 + h * DINO_ + off;
    #pragma unroll
    for (int t = 0; t < 12; ++t) {
      const float4 v = *(const float4*)(qb + 32 * t);
      qr[4*t] = v.x; qr[4*t+1] = v.y; qr[4*t+2] = v.z; qr[4*t+3] = v.w;
    }
  }
  float s[48];
  #pragma unroll
  for (int k = 0; k < 48; ++k) s[k] = 0.0f;
  float l = 0.0f;

  const float* dbase = dino + (size_t)b * N_ * DINO_ + off;

  #pragma unroll 1
  for (int n = n0 + w; n < n1; n += 4) {
    const float* row = dbase + (size_t)n * DINO_;
    float4 x[12];
    #pragma unroll
    for (int t = 0; t < 12; ++t) x[t] = *(const float4*)(row + 32 * t);

    float a0 = 0.f, a1 = 0.f, a2 = 0.f, a3 = 0.f;
    #pragma unroll
    for (int t = 0; t < 12; ++t) {
      a0 += qr[4*t]   * x[t].x;
      a1 += qr[4*t+1] * x[t].y;
      a2 += qr[4*t+2] * x[t].z;
      a3 += qr[4*t+3] * x[t].w;
    }
    float v = (a0 + a1) + (a2 + a3);
    v += __shfl_xor(v, 1);
    v += __shfl_xor(v, 2);
    v += __shfl_xor(v, 4);          // all 8 lanes of the head now hold the logit
    const float p = __expf(v);
    l += p;
    #pragma unroll
    for (int t = 0; t < 12; ++t) {
      s[4*t]   += p * x[t].x;
      s[4*t+1] += p * x[t].y;
      s[4*t+2] += p * x[t].z;
      s[4*t+3] += p * x[t].w;
    }
  }

  // ---- staged merge of 4 waves (plain sums; no max algebra needed) ----
  __shared__ float sm[2][64 * SMP];
  __shared__ float lm[2][H_];
  if (w >= 2) {
    float* dst = &sm[w - 2][lane * SMP];
    #pragma unroll
    for (int t = 0; t < 12; ++t)
      *(float4*)(dst + 4 * t) = make_float4(s[4*t], s[4*t+1], s[4*t+2], s[4*t+3]);
    if (sl == 0) lm[w - 2][h] = l;
  }
  __syncthreads();
  if (w < 2) {
    const float* src = &sm[w][lane * SMP];
    #pragma unroll
    for (int t = 0; t < 12; ++t) {
      const float4 v = *(const float4*)(src + 4 * t);
      s[4*t] += v.x; s[4*t+1] += v.y; s[4*t+2] += v.z; s[4*t+3] += v.w;
    }
    l += lm[w][h];
  }
  __syncthreads();
  if (w == 1) {
    float* dst = &sm[0][lane * SMP];
    #pragma unroll
    for (int t = 0; t < 12; ++t)
      *(float4*)(dst + 4 * t) = make_float4(s[4*t], s[4*t+1], s[4*t+2], s[4*t+3]);
    if (sl == 0) lm[0][h] = l;
  }
  __syncthreads();
  if (w == 0) {
    const float* src = &sm[0][lane * SMP];
    #pragma unroll
    for (int t = 0; t < 12; ++t) {
      const float4 v = *(const float4*)(src + 4 * t);
      s[4*t] += v.x; s[4*t+1] += v.y; s[4*t+2] += v.z; s[4*t+3] += v.w;
    }
    l += lm[0][h];
    float* pso = ps + (size_t)blk * 3072 + h * DINO_ + off;
    #pragma unroll
    for (int t = 0; t < 12; ++t)
      *(float4*)(pso + 32 * t) = make_float4(s[4*t], s[4*t+1], s[4*t+2], s[4*t+3]);
    if (sl == 0) pl[blk * H_ + h] = l;
  }
}

// ---------------------------------------------------------------------------
// kmf: fused chunk-merge + normalize + V-projection + LayerNorm.
// grid 128 x 512.
// ---------------------------------------------------------------------------
__global__ __launch_bounds__(512) void kmf(const float* __restrict__ ps,
                                           const float* __restrict__ pl,
                                           const float* __restrict__ Wv,
                                           const float* __restrict__ bv,
                                           const float* __restrict__ gamma,
                                           const float* __restrict__ beta,
                                           float* __restrict__ out) {
  const int b = blockIdx.x, tid = threadIdx.x;
  __shared__ float sfl[3072];
  __shared__ float rL[H_];
  float a[6];
  #pragma unroll
  for (int r = 0; r < 6; ++r) {
    const int e = tid + 512 * r;
    float acc = 0.0f;
    #pragma unroll
    for (int cc = 0; cc < CHUNKS; ++cc)
      acc += ps[(size_t)(b * CHUNKS + cc) * 3072 + e];
    a[r] = acc;
  }
  if (tid < H_) {
    float L = 0.0f;
    #pragma unroll
    for (int cc = 0; cc < CHUNKS; ++cc) L += pl[(b * CHUNKS + cc) * H_ + tid];
    rL[tid] = 1.0f / L;
  }
  __syncthreads();
  #pragma unroll
  for (int r = 0; r < 6; ++r) {
    const int e = tid + 512 * r;
    sfl[e] = a[r] * rL[e / DINO_];
  }
  __syncthreads();
  const int w = tid >> 6, lane = tid & 63;
  const float* srow = sfl + (tid >> 6) * DINO_;
  float acc = bv[tid];
  #pragma unroll 8
  for (int d = 0; d < DINO_; ++d) acc += srow[d] * Wv[d * CLIP_ + tid];
  // LayerNorm over 512
  float sum = wave_sum(acc);
  float sq  = wave_sum(acc * acc);
  __shared__ float rS[8], rQ[8];
  if (lane == 0) { rS[w] = sum; rQ[w] = sq; }
  __syncthreads();
  float tot = 0.0f, totq = 0.0f;
  #pragma unroll
  for (int i = 0; i < 8; ++i) { tot += rS[i]; totq += rQ[i]; }
  const float mu = tot * (1.0f / 512.0f);
  const float var = totq * (1.0f / 512.0f) - mu * mu;
  const float rstd = rsqrtf(var + 1e-5f);
  out[(size_t)b * CLIP_ + tid] = (acc - mu) * rstd * gamma[tid] + beta[tid];
}

// ---------------------------------------------------------------------------
extern "C" void kernel_launch(void* const* d_in, const int* in_sizes, int n_in,
                              void* d_out, int out_size, void* d_ws, size_t ws_size,
                              hipStream_t stream) {
  const float* dino  = (const float*)d_in[0];
  const float* clip  = (const float*)d_in[1];
  const float* Wq    = (const float*)d_in[2];
  const float* bq    = (const float*)d_in[3];
  const float* Wk    = (const float*)d_in[4];
  // d_in[5] = bk: softmax shift-invariant, dropped
  const float* Wv    = (const float*)d_in[6];
  const float* bv    = (const float*)d_in[7];
  const float* temp  = (const float*)d_in[8];
  const float* gamma = (const float*)d_in[9];
  const float* beta  = (const float*)d_in[10];
  float* out = (float*)d_out;

  float* ws  = (float*)d_ws;
  float* Q   = ws;                       // 128*512            =    65,536 f
  float* qkb = Q   + 65536;              // 128*3072           =   393,216 f
  float* ps  = qkb + 393216;             // 128*6*3072         = 2,359,296 f
  float* pl  = ps  + 2359296;            // 128*6*8            =     6,144 f
  // total ~11.3 MB

  kq   <<<dim3(B_, 2),  256, 0, stream>>>(clip, Wq, bq, Q);
  kqk  <<<dim3(B_, 12), 256, 0, stream>>>(Wk, Q, temp, qkb);
  kmain<<<B_ * CHUNKS,  256, 0, stream>>>(dino, qkb, ps, pl);
  kmf  <<<B_,           512, 0, stream>>>(ps, pl, Wv, bv, gamma, beta, out);
}

// Round 2
// 474.337 us; speedup vs baseline: 1.1341x; 1.1341x over previous
//
#include <hip/hip_runtime.h>
#include <math.h>
#include <stdint.h>

#define B_    128
#define N_    1369
#define DINO_ 384
#define CLIP_ 512
#define H_    8
#define CHUNKS 6
#define CH     229   // ceil(1369/6); last chunk = 224
#define SMP    52    // padded per-lane float stride in merge LDS (16B aligned, conflict-free)
#define TROWS  16    // rows per LDS stage tile (16*384*4B = 24 KiB per buffer)

// ---------------------------------------------------------------------------
// helpers
// ---------------------------------------------------------------------------
__device__ __forceinline__ float wave_sum(float v) {
  v += __shfl_xor(v, 1);  v += __shfl_xor(v, 2);  v += __shfl_xor(v, 4);
  v += __shfl_xor(v, 8);  v += __shfl_xor(v, 16); v += __shfl_xor(v, 32);
  return v;
}

// async global->LDS copy, 16B per lane. LDS dest = base + lane*16 (HW rule).
__device__ __forceinline__ void gld16(const float* g, float* lds_base) {
  __builtin_amdgcn_global_load_lds(
      (const __attribute__((address_space(1))) void*)g,
      (__attribute__((address_space(3))) void*)lds_base, 16, 0, 0);
}

// ---------------------------------------------------------------------------
// kq: Q[b,c] = bq[c] + clip[b,:]·Wq[:,c].  grid (128,2) x 256.
// ---------------------------------------------------------------------------
__global__ __launch_bounds__(256) void kq(const float* __restrict__ clip,
                                          const float* __restrict__ Wq,
                                          const float* __restrict__ bq,
                                          float* __restrict__ Q) {
  const int b = blockIdx.x;
  const int c = blockIdx.y * 256 + threadIdx.x;
  __shared__ float cl[CLIP_];
  cl[threadIdx.x] = clip[b * CLIP_ + threadIdx.x];
  cl[threadIdx.x + 256] = clip[b * CLIP_ + threadIdx.x + 256];
  __syncthreads();
  float acc = bq[c];
  #pragma unroll 8
  for (int j = 0; j < CLIP_; ++j) acc += cl[j] * Wq[j * CLIP_ + c];
  Q[b * CLIP_ + c] = acc;
}

// ---------------------------------------------------------------------------
// kqk: qk[b, h*384+j] = rs * sum_d Wk[j][h*64+d] * Q[b, h*64+d].
// grid (128,12) x 256.
// ---------------------------------------------------------------------------
__global__ __launch_bounds__(256) void kqk(const float* __restrict__ Wk,
                                           const float* __restrict__ Q,
                                           const float* __restrict__ temp,
                                           float* __restrict__ qkout) {
  const int b = blockIdx.x;
  const int e = blockIdx.y * 256 + threadIdx.x;   // 0..3071
  __shared__ float qs[CLIP_];
  qs[threadIdx.x] = Q[b * CLIP_ + threadIdx.x];
  qs[threadIdx.x + 256] = Q[b * CLIP_ + threadIdx.x + 256];
  __syncthreads();
  const int h = e / DINO_;
  const int j = e - h * DINO_;
  const float rs = 1.0f / (8.0f * temp[0]);       // scale = sqrt(64)*temperature
  const float* wrow = Wk + (size_t)j * CLIP_ + h * 64;
  const float* qrow = qs + h * 64;
  float a0 = 0.f, a1 = 0.f, a2 = 0.f, a3 = 0.f;
  #pragma unroll
  for (int d = 0; d < 64; d += 4) {
    const float4 wv = *(const float4*)(wrow + d);
    const float4 qv = *(const float4*)(qrow + d);
    a0 += wv.x * qv.x;  a1 += wv.y * qv.y;
    a2 += wv.z * qv.z;  a3 += wv.w * qv.w;
  }
  qkout[(size_t)b * 3072 + e] = ((a0 + a1) + (a2 + a3)) * rs;
}

// ---------------------------------------------------------------------------
// kmain: fused logits + (no-max) softmax numerator + attn-weighted dino sum.
// grid 768 x 256 (exactly 3 blocks/CU).
//
// v2 structure: double-buffered LDS staging of TROWS-row dino tiles via
// global_load_lds (linear, coalesced, no duplicated addresses on the HBM
// path).  Compute reads each row from LDS: lane layout h=lane>>3, sl=lane&7,
// dims 4*(sl+8t)+z.  Per ds_read_b128 the wave touches 8 distinct contiguous
// 16B slots (banks 0..31 exactly once) with 8x same-address broadcast (free).
// Head logit reduction = 3 xor-shuffles (DPP-class, cheap).
// ---------------------------------------------------------------------------
__global__ __launch_bounds__(256, 3) void kmain(const float* __restrict__ dino,
                                                const float* __restrict__ qk,
                                                float* __restrict__ ps,
                                                float* __restrict__ pl) {
  __shared__ float lds[2 * TROWS * DINO_];   // 2 x 6144 floats = 48 KiB
  __shared__ float lm[2][H_];

  const int blk = blockIdx.x;
  const int b = blk / CHUNKS;
  const int c = blk - b * CHUNKS;
  const int n0 = c * CH;
  const int n1 = min(N_, n0 + CH);
  const int tid = threadIdx.x, w = tid >> 6, lane = tid & 63;
  const int h = lane >> 3, sl = lane & 7;
  const int off = 4 * sl;

  // qk fragment: qr[4t+z] = qk[b][h*384 + 32t + 4sl + z]
  float qr[48];
  {
    const float* qb = qk + (size_t)b * 3072 + h * DINO_ + off;
    #pragma unroll
    for (int t = 0; t < 12; ++t) {
      const float4 v = *(const float4*)(qb + 32 * t);
      qr[4*t] = v.x; qr[4*t+1] = v.y; qr[4*t+2] = v.z; qr[4*t+3] = v.w;
    }
  }
  float s[48];
  #pragma unroll
  for (int k = 0; k < 48; ++k) s[k] = 0.0f;
  float l = 0.0f;

  const float* gdino = dino + (size_t)b * N_ * DINO_;
  const float* gclamp = dino + ((size_t)B_ * N_ * DINO_ - 4); // last safe float4
  const int ntiles = (n1 - n0 + TROWS - 1) / TROWS;

  // stage tile 0 into buf0: 24 segments of 64 float4; wave w issues 6.
  {
    const float* gb = gdino + (size_t)n0 * DINO_;
    #pragma unroll
    for (int j = 0; j < 6; ++j) {
      const int seg = 6 * w + j;
      const float* g = gb + (size_t)(seg * 64 + lane) * 4;
      if (g > gclamp) g = gclamp;
      gld16(g, lds + seg * 256);
    }
  }
  __syncthreads();

  for (int t = 0; t < ntiles; ++t) {
    float* cur = lds + ((t & 1) ? TROWS * DINO_ : 0);
    float* nxt = lds + ((t & 1) ? 0 : TROWS * DINO_);
    if (t + 1 < ntiles) {
      const float* gb = gdino + (size_t)(n0 + (t + 1) * TROWS) * DINO_;
      #pragma unroll
      for (int j = 0; j < 6; ++j) {
        const int seg = 6 * w + j;
        const float* g = gb + (size_t)(seg * 64 + lane) * 4;
        if (g > gclamp) g = gclamp;
        gld16(g, nxt + seg * 256);
      }
    }
    const int tb = n0 + t * TROWS;
    #pragma unroll 1
    for (int k = 0; k < 4; ++k) {
      const int slot = w + 4 * k;
      if (tb + slot >= n1) break;           // wave-uniform
      const float* xr = cur + slot * DINO_ + off;
      float4 x[12];
      #pragma unroll
      for (int u = 0; u < 12; ++u) x[u] = *(const float4*)(xr + 32 * u);

      float a0 = 0.f, a1 = 0.f, a2 = 0.f, a3 = 0.f;
      #pragma unroll
      for (int u = 0; u < 12; ++u) {
        a0 += qr[4*u]   * x[u].x;
        a1 += qr[4*u+1] * x[u].y;
        a2 += qr[4*u+2] * x[u].z;
        a3 += qr[4*u+3] * x[u].w;
      }
      float v = (a0 + a1) + (a2 + a3);
      v += __shfl_xor(v, 1);
      v += __shfl_xor(v, 2);
      v += __shfl_xor(v, 4);                // 8 lanes of the head share the logit
      const float p = __expf(v);
      l += p;
      #pragma unroll
      for (int u = 0; u < 12; ++u) {
        s[4*u]   += p * x[u].x;
        s[4*u+1] += p * x[u].y;
        s[4*u+2] += p * x[u].z;
        s[4*u+3] += p * x[u].w;
      }
    }
    __syncthreads();   // stage t+1 complete + cur free for overwrite at t+2
  }

  // ---- staged merge of 4 waves (aliased into the stage LDS; loop is done) ----
  float* sm0 = lds;                 // 64*SMP floats
  float* sm1 = lds + 64 * SMP;      // 2*64*52 = 6656 floats << 12288 available
  if (w >= 2) {
    float* dst = (w == 2 ? sm0 : sm1) + lane * SMP;
    #pragma unroll
    for (int t = 0; t < 12; ++t)
      *(float4*)(dst + 4 * t) = make_float4(s[4*t], s[4*t+1], s[4*t+2], s[4*t+3]);
    if (sl == 0) lm[w - 2][h] = l;
  }
  __syncthreads();
  if (w < 2) {
    const float* src = (w == 0 ? sm0 : sm1) + lane * SMP;
    #pragma unroll
    for (int t = 0; t < 12; ++t) {
      const float4 v = *(const float4*)(src + 4 * t);
      s[4*t] += v.x; s[4*t+1] += v.y; s[4*t+2] += v.z; s[4*t+3] += v.w;
    }
    l += lm[w][h];
  }
  __syncthreads();
  if (w == 1) {
    float* dst = sm0 + lane * SMP;
    #pragma unroll
    for (int t = 0; t < 12; ++t)
      *(float4*)(dst + 4 * t) = make_float4(s[4*t], s[4*t+1], s[4*t+2], s[4*t+3]);
    if (sl == 0) lm[0][h] = l;
  }
  __syncthreads();
  if (w == 0) {
    const float* src = sm0 + lane * SMP;
    #pragma unroll
    for (int t = 0; t < 12; ++t) {
      const float4 v = *(const float4*)(src + 4 * t);
      s[4*t] += v.x; s[4*t+1] += v.y; s[4*t+2] += v.z; s[4*t+3] += v.w;
    }
    l += lm[0][h];
    float* pso = ps + (size_t)blk * 3072 + h * DINO_ + off;
    #pragma unroll
    for (int t = 0; t < 12; ++t)
      *(float4*)(pso + 32 * t) = make_float4(s[4*t], s[4*t+1], s[4*t+2], s[4*t+3]);
    if (sl == 0) pl[blk * H_ + h] = l;
  }
}

// ---------------------------------------------------------------------------
// kmf: fused chunk-merge + normalize + V-projection + LayerNorm.
// grid 128 x 512.
// ---------------------------------------------------------------------------
__global__ __launch_bounds__(512) void kmf(const float* __restrict__ ps,
                                           const float* __restrict__ pl,
                                           const float* __restrict__ Wv,
                                           const float* __restrict__ bv,
                                           const float* __restrict__ gamma,
                                           const float* __restrict__ beta,
                                           float* __restrict__ out) {
  const int b = blockIdx.x, tid = threadIdx.x;
  __shared__ float sfl[3072];
  __shared__ float rL[H_];
  float a[6];
  #pragma unroll
  for (int r = 0; r < 6; ++r) {
    const int e = tid + 512 * r;
    float acc = 0.0f;
    #pragma unroll
    for (int cc = 0; cc < CHUNKS; ++cc)
      acc += ps[(size_t)(b * CHUNKS + cc) * 3072 + e];
    a[r] = acc;
  }
  if (tid < H_) {
    float L = 0.0f;
    #pragma unroll
    for (int cc = 0; cc < CHUNKS; ++cc) L += pl[(b * CHUNKS + cc) * H_ + tid];
    rL[tid] = 1.0f / L;
  }
  __syncthreads();
  #pragma unroll
  for (int r = 0; r < 6; ++r) {
    const int e = tid + 512 * r;
    sfl[e] = a[r] * rL[e / DINO_];
  }
  __syncthreads();
  const int w = tid >> 6, lane = tid & 63;
  const float* srow = sfl + (tid >> 6) * DINO_;
  float acc = bv[tid];
  #pragma unroll 8
  for (int d = 0; d < DINO_; ++d) acc += srow[d] * Wv[d * CLIP_ + tid];
  // LayerNorm over 512
  float sum = wave_sum(acc);
  float sq  = wave_sum(acc * acc);
  __shared__ float rS[8], rQ[8];
  if (lane == 0) { rS[w] = sum; rQ[w] = sq; }
  __syncthreads();
  float tot = 0.0f, totq = 0.0f;
  #pragma unroll
  for (int i = 0; i < 8; ++i) { tot += rS[i]; totq += rQ[i]; }
  const float mu = tot * (1.0f / 512.0f);
  const float var = totq * (1.0f / 512.0f) - mu * mu;
  const float rstd = rsqrtf(var + 1e-5f);
  out[(size_t)b * CLIP_ + tid] = (acc - mu) * rstd * gamma[tid] + beta[tid];
}

// ---------------------------------------------------------------------------
extern "C" void kernel_launch(void* const* d_in, const int* in_sizes, int n_in,
                              void* d_out, int out_size, void* d_ws, size_t ws_size,
                              hipStream_t stream) {
  const float* dino  = (const float*)d_in[0];
  const float* clip  = (const float*)d_in[1];
  const float* Wq    = (const float*)d_in[2];
  const float* bq    = (const float*)d_in[3];
  const float* Wk    = (const float*)d_in[4];
  // d_in[5] = bk: softmax shift-invariant, dropped
  const float* Wv    = (const float*)d_in[6];
  const float* bv    = (const float*)d_in[7];
  const float* temp  = (const float*)d_in[8];
  const float* gamma = (const float*)d_in[9];
  const float* beta  = (const float*)d_in[10];
  float* out = (float*)d_out;

  float* ws  = (float*)d_ws;
  float* Q   = ws;                       // 128*512            =    65,536 f
  float* qkb = Q   + 65536;              // 128*3072           =   393,216 f
  float* ps  = qkb + 393216;             // 128*6*3072         = 2,359,296 f
  float* pl  = ps  + 2359296;            // 128*6*8            =     6,144 f
  // total ~11.3 MB

  kq   <<<dim3(B_, 2),  256, 0, stream>>>(clip, Wq, bq, Q);
  kqk  <<<dim3(B_, 12), 256, 0, stream>>>(Wk, Q, temp, qkb);
  kmain<<<B_ * CHUNKS,  256, 0, stream>>>(dino, qkb, ps, pl);
  kmf  <<<B_,           512, 0, stream>>>(ps, pl, Wv, bv, gamma, beta, out);
}